// Round 3
// baseline (1269.716 us; speedup 1.0000x reference)
//
#include <hip/hip_runtime.h>
#include <math.h>

#define BB 32
#define TT 2048
#define DD 1024   // HID == OUT == DV == 1024
#define HF 512    // OUT/2

#define QKS 32            // k-split chunks for query projection
#define QCH (DD / QKS)    // 32 h per chunk

#define TCH 64            // t-chunks for context
#define TCHUNK (TT / TCH) // 32 rows per chunk

#define NB   1024         // persistent grid: 4 blocks/CU on 256 CUs
#define NTHR 256

// ---------------------------------------------------------------------------
__device__ __forceinline__ float tanh_fast(float x) {
    float e = __expf(2.0f * x);
    return 1.0f - 2.0f / (e + 1.0f);
}

// Sense-reversing grid barrier. bar[0]=count, bar[1]=generation (zeroed per launch).
// Deadman-bounded spin: a scheduling pathology yields wrong output, not a hang.
__device__ __forceinline__ void grid_barrier(int* bar) {
    __syncthreads();
    if (threadIdx.x == 0) {
        __threadfence();   // release: make this block's writes visible device-wide
        int g = __hip_atomic_load(bar + 1, __ATOMIC_RELAXED, __HIP_MEMORY_SCOPE_AGENT);
        int prev = __hip_atomic_fetch_add(bar, 1, __ATOMIC_ACQ_REL, __HIP_MEMORY_SCOPE_AGENT);
        if (prev == NB - 1) {
            __hip_atomic_store(bar, 0, __ATOMIC_RELAXED, __HIP_MEMORY_SCOPE_AGENT);
            __hip_atomic_store(bar + 1, g + 1, __ATOMIC_RELEASE, __HIP_MEMORY_SCOPE_AGENT);
        } else {
            long spins = 0;
            while (__hip_atomic_load(bar + 1, __ATOMIC_ACQUIRE, __HIP_MEMORY_SCOPE_AGENT) == g) {
                __builtin_amdgcn_s_sleep(8);
                if (++spins > (1L << 22)) break;
            }
        }
        __threadfence();   // acquire
    }
    __syncthreads();
}

// ---------------------------------------------------------------------------
__global__ void __launch_bounds__(NTHR, 4) fused_attention_kernel(
        const float* __restrict__ hidden, const float* __restrict__ key,
        const float* __restrict__ value, const int* __restrict__ seq_lens,
        const float* __restrict__ Wq, const float* __restrict__ bq,
        const float* __restrict__ W1, const float* __restrict__ b1,
        const float* __restrict__ W2, const float* __restrict__ b2,
        float* __restrict__ ctx, float* __restrict__ attn,
        float* __restrict__ w, float* __restrict__ cb,
        float* __restrict__ query, float* __restrict__ qpart,
        float* __restrict__ escore, float* __restrict__ psum,
        float* __restrict__ partial, int* __restrict__ bar) {
    __shared__ float smem[BB * QCH];   // 1024 floats / 4 KB, reused per phase
    const int bx = blockIdx.x, tid = threadIdx.x;
    const int wave = tid >> 6, lane = tid & 63;

    // ======== P0: w = W1@W2 (blocks 0-3); cbias (block 4); query partials (5-132)
    if (bx < 4) {
        int d = bx * 256 + tid;
        const float* row = W1 + (size_t)d * HF;
        float acc = 0.0f;
        #pragma unroll 4
        for (int j = 0; j < HF; j += 4) {
            float4 a = *(const float4*)(row + j);
            float4 b = *(const float4*)(W2 + j);
            acc += a.x * b.x + a.y * b.y + a.z * b.z + a.w * b.w;
        }
        w[d] = acc;
    } else if (bx == 4) {
        float s = b1[tid] * W2[tid] + b1[tid + 256] * W2[tid + 256];
        smem[tid] = s;
        __syncthreads();
        for (int off = 128; off; off >>= 1) {
            if (tid < off) smem[tid] += smem[tid + off];
            __syncthreads();
        }
        if (tid == 0) cb[0] = smem[0] + b2[0];
    } else if (bx < 133) {
        int idx = bx - 5, otile = idx & 3, ks = idx >> 2;
        int o = otile * 256 + tid, h0 = ks * QCH;
        { int r = tid >> 3, c4 = (tid & 7) << 2;
          *(float4*)&smem[r * QCH + c4] = *(const float4*)&hidden[(size_t)r * DD + h0 + c4]; }
        __syncthreads();
        float acc[BB];
        #pragma unroll
        for (int b = 0; b < BB; ++b) acc[b] = 0.0f;
        for (int h = 0; h < QCH; ++h) {
            float wv = Wq[(size_t)(h0 + h) * DD + o];
            #pragma unroll
            for (int b = 0; b < BB; ++b) acc[b] = fmaf(smem[b * QCH + h], wv, acc[b]);
        }
        #pragma unroll
        for (int b = 0; b < BB; ++b) qpart[((size_t)ks * BB + b) * DD + o] = acc[b];
    }
    grid_barrier(bar);

    // ======== P1: query[b,o] = bq[o] + sum_ks qpart
    if (bx < 128) {
        int i = bx * 256 + tid;
        int o = i & (DD - 1);
        float acc = bq[o];
        #pragma unroll
        for (int ks = 0; ks < QKS; ++ks) acc += qpart[(size_t)ks * (BB * DD) + i];
        query[i] = acc;
    }
    grid_barrier(bar);

    // ======== P2: e[b,t] = exp(score) (no max shift: |score| <= ~9 analytically),
    //              psum[b,chunk16] partial sums. Masked rows -> e = 0.
    {
        float c0 = cb[0];
        for (int item = bx; item < BB * (TT / 16); item += NB) {   // 4096 items
            int b = item >> 7, ch = item & 127;
            int t0 = ch * 16;
            int len = seq_lens[b];
            const float* qrow = query + (size_t)b * DD;
            float wave_sum = 0.0f;
            #pragma unroll
            for (int tt = 0; tt < 4; ++tt) {
                int t = t0 + tt * 4 + wave;
                float e = 0.0f;
                if (t < len) {
                    const float* krow = key + ((size_t)b * TT + t) * DD;
                    float acc = 0.0f;
                    #pragma unroll
                    for (int kb = 0; kb < 4; ++kb) {
                        int d = kb * 256 + lane * 4;
                        float4 kv = *(const float4*)(krow + d);
                        float4 qv = *(const float4*)(qrow + d);
                        float4 wv = *(const float4*)(w + d);
                        acc += tanh_fast(kv.x + qv.x) * wv.x;
                        acc += tanh_fast(kv.y + qv.y) * wv.y;
                        acc += tanh_fast(kv.z + qv.z) * wv.z;
                        acc += tanh_fast(kv.w + qv.w) * wv.w;
                    }
                    #pragma unroll
                    for (int off = 32; off; off >>= 1) acc += __shfl_down(acc, off);
                    if (lane == 0) {
                        e = __expf(acc + c0);
                        escore[(size_t)b * TT + t] = e;
                    }
                } else {
                    if (lane == 0) escore[(size_t)b * TT + t] = 0.0f;
                }
                wave_sum += e;   // nonzero only on lane 0
            }
            if (lane == 0) smem[wave] = wave_sum;
            __syncthreads();
            if (tid == 0) psum[b * 128 + ch] = smem[0] + smem[1] + smem[2] + smem[3];
            __syncthreads();
        }
    }
    grid_barrier(bar);

    // ======== P3: S[b] (fixed-order reduce of psum), attn = e/S, context partials
    for (int item = bx; item < BB * TCH; item += NB) {   // 2048 items
        int b = item >> 6, tch = item & 63;
        int len = seq_lens[b];
        if (tid < 128) smem[tid] = psum[b * 128 + tid];
        __syncthreads();
        for (int off = 64; off; off >>= 1) {
            if (tid < off) smem[tid] += smem[tid + off];
            __syncthreads();
        }
        float Sinv = 1.0f / smem[0];
        int t0 = tch * TCHUNK;
        if (tid < TCHUNK)
            attn[(size_t)b * TT + t0 + tid] = escore[(size_t)b * TT + t0 + tid] * Sinv;
        if (t0 < len) {
            int tend = min(t0 + TCHUNK, len);
            int d4 = tid * 4;
            const float* vbase = value + (size_t)b * TT * DD + d4;
            float4 acc = {0.0f, 0.0f, 0.0f, 0.0f};
            for (int t = t0; t < tend; ++t) {
                float a = escore[(size_t)b * TT + t] * Sinv;
                float4 vv = *(const float4*)(vbase + (size_t)t * DD);
                acc.x = fmaf(a, vv.x, acc.x);
                acc.y = fmaf(a, vv.y, acc.y);
                acc.z = fmaf(a, vv.z, acc.z);
                acc.w = fmaf(a, vv.w, acc.w);
            }
            *(float4*)&partial[((size_t)(b * TCH + tch)) * DD + d4] = acc;
        }
        __syncthreads();   // smem reuse across items
    }
    grid_barrier(bar);

    // ======== P4: ctx[b,d] = sum over live chunks
    if (bx < 128) {
        int i = bx * 256 + tid;
        int b = i >> 10, d = i & 1023;
        int len = seq_lens[b];
        int nch = min(TCH, (len + TCHUNK - 1) / TCHUNK);
        float acc = 0.0f;
        for (int c = 0; c < nch; ++c)
            acc += partial[((size_t)(b * TCH + c)) * DD + d];
        ctx[(size_t)b * DD + d] = acc;
    }
}

// ---------------------------------------------------------------------------
extern "C" void kernel_launch(void* const* d_in, const int* in_sizes, int n_in,
                              void* d_out, int out_size, void* d_ws, size_t ws_size,
                              hipStream_t stream) {
    const float* hidden   = (const float*)d_in[0];
    const float* key      = (const float*)d_in[1];
    const float* value    = (const float*)d_in[2];
    const int*   seq_lens = (const int*)  d_in[3];
    const float* Wq       = (const float*)d_in[4];
    const float* bq       = (const float*)d_in[5];
    const float* W1       = (const float*)d_in[6];
    const float* b1       = (const float*)d_in[7];
    const float* W2       = (const float*)d_in[8];
    const float* b2       = (const float*)d_in[9];

    float* out  = (float*)d_out;
    float* ctx  = out;                 // [32*1024]
    float* attn = out + BB * DD;       // [32*2048]

    int*   bar     = (int*)d_ws;                       // 2 ints (zeroed below)
    float* fbase   = (float*)d_ws + 64;
    float* w       = fbase;                            // 1024
    float* cb      = fbase + 1024;                     // 1 (padded to 1024)
    float* query   = fbase + 2048;                     // 32768
    float* qpart   = query + BB * DD;                  // 32*32*1024
    float* escore  = qpart + (size_t)QKS * BB * DD;    // 65536
    float* psum    = escore + BB * TT;                 // 32*128 = 4096
    float* partial = psum + BB * 128;                  // 32*64*1024

    hipMemsetAsync(bar, 0, 2 * sizeof(int), stream);
    fused_attention_kernel<<<dim3(NB), dim3(NTHR), 0, stream>>>(
        hidden, key, value, seq_lens, Wq, bq, W1, b1, W2, b2,
        ctx, attn, w, cb, query, qpart, escore, psum, partial, bar);
}

// Round 4
// 106.966 us; speedup vs baseline: 11.8702x; 11.8702x over previous
//
#include <hip/hip_runtime.h>
#include <math.h>

#define BB 32
#define TT 2048
#define DD 1024   // HID == OUT == DV == 1024
#define HF 512    // OUT/2

#define QKS 32            // k-split chunks for query projection
#define QCH (DD / QKS)    // 32 h per chunk

#define CHK 32            // t-rows per fused score+context chunk
#define NCH (TT / CHK)    // 64 chunks

// ---------------------------------------------------------------------------
__device__ __forceinline__ float tanh_fast(float x) {
    float e = __expf(2.0f * x);
    return 1.0f - 2.0f / (e + 1.0f);
}

// ---------------------------------------------------------------------------
// blocks 0..3: w[d]=sum_j W1[d,j]*W2[j]; block 4: cbias; blocks 5..132: qpart
__global__ void __launch_bounds__(256) prep_query_kernel(
        const float* __restrict__ hidden, const float* __restrict__ Wq,
        const float* __restrict__ W1, const float* __restrict__ b1,
        const float* __restrict__ W2, const float* __restrict__ b2,
        float* __restrict__ w, float* __restrict__ cbias,
        float* __restrict__ qpart) {
    __shared__ float smem[BB * QCH];   // 4 KB
    int bx  = blockIdx.x;
    int tid = threadIdx.x;

    if (bx < 4) {                                   // ---- w = W1 @ W2
        int d = bx * 256 + tid;
        const float* row = W1 + (size_t)d * HF;
        float acc = 0.0f;
        #pragma unroll 4
        for (int j = 0; j < HF; j += 4) {
            float4 a = *(const float4*)(row + j);
            float4 b = *(const float4*)(W2 + j);
            acc += a.x * b.x + a.y * b.y + a.z * b.z + a.w * b.w;
        }
        w[d] = acc;
        return;
    }
    if (bx == 4) {                                  // ---- cbias
        float s = b1[tid] * W2[tid] + b1[tid + 256] * W2[tid + 256];
        smem[tid] = s;
        __syncthreads();
        for (int off = 128; off; off >>= 1) {
            if (tid < off) smem[tid] += smem[tid + off];
            __syncthreads();
        }
        if (tid == 0) cbias[0] = smem[0] + b2[0];
        return;
    }
    // ---- query partial
    int idx = bx - 5, otile = idx & 3, ks = idx >> 2;
    int o = otile * 256 + tid, h0 = ks * QCH;
    { int r = tid >> 3, c4 = (tid & 7) << 2;
      *(float4*)&smem[r * QCH + c4] = *(const float4*)&hidden[(size_t)r * DD + h0 + c4]; }
    __syncthreads();
    float acc[BB];
    #pragma unroll
    for (int b = 0; b < BB; ++b) acc[b] = 0.0f;
    for (int h = 0; h < QCH; ++h) {
        float wv = Wq[(size_t)(h0 + h) * DD + o];
        #pragma unroll
        for (int b = 0; b < BB; ++b)
            acc[b] = fmaf(smem[b * QCH + h], wv, acc[b]);
    }
    #pragma unroll
    for (int b = 0; b < BB; ++b)
        qpart[((size_t)ks * BB + b) * DD + o] = acc[b];
}

// ---------------------------------------------------------------------------
// query[b,o] = bq[o] + sum_ks qpart[ks][b][o]
__global__ void __launch_bounds__(256) qreduce_kernel(
        const float* __restrict__ qpart, const float* __restrict__ bq,
        float* __restrict__ query) {
    int i = blockIdx.x * 256 + threadIdx.x;   // grid 128
    int o = i & (DD - 1);
    float acc = bq[o];
    #pragma unroll
    for (int ks = 0; ks < QKS; ++ks)
        acc += qpart[(size_t)ks * (BB * DD) + i];
    query[i] = acc;
}

// ---------------------------------------------------------------------------
// Fused scores + unnormalized context partials, one chunk of 32 t-rows:
//   e[t]           = exp(cb + sum_d tanh(key+query)*w)      (no max shift)
//   escore[b,t]    = e[t]                  (0 for t>=len inside live chunk)
//   psum[b,chunk]  = sum_t e[t]
//   partial[b,ch,d]= sum_t e[t]*value[b,t,d]
// Chunks entirely past len exit immediately (finalize never reads them).
__global__ void __launch_bounds__(256) score_ctx_kernel(
        const float* __restrict__ key, const float* __restrict__ value,
        const float* __restrict__ query, const float* __restrict__ w,
        const float* __restrict__ cb, const int* __restrict__ seq_lens,
        float* __restrict__ escore, float* __restrict__ psum,
        float* __restrict__ partial) {
    int b   = blockIdx.y;
    int len = seq_lens[b];
    int t0  = blockIdx.x * CHK;
    if (t0 >= len) return;

    __shared__ float wsh[DD];
    __shared__ float qsh[DD];
    __shared__ float esm[CHK];
    int tid = threadIdx.x;
    { int i4 = tid * 4;
      *(float4*)&wsh[i4] = *(const float4*)&w[i4];
      *(float4*)&qsh[i4] = *(const float4*)&query[(size_t)b * DD + i4]; }
    __syncthreads();

    int wave = tid >> 6, lane = tid & 63;
    float c0 = cb[0];

    // ---- scores: wave handles rows r = tt*4 + wave
    #pragma unroll
    for (int tt = 0; tt < CHK / 4; ++tt) {
        int r = tt * 4 + wave;
        int t = t0 + r;
        float e = 0.0f;
        if (t < len) {
            const float* krow = key + ((size_t)b * TT + t) * DD;
            float acc = 0.0f;
            #pragma unroll
            for (int kb = 0; kb < 4; ++kb) {
                int d = kb * 256 + lane * 4;
                float4 kv = *(const float4*)(krow + d);
                float4 qv = *(const float4*)&qsh[d];
                float4 wv = *(const float4*)&wsh[d];
                acc += tanh_fast(kv.x + qv.x) * wv.x;
                acc += tanh_fast(kv.y + qv.y) * wv.y;
                acc += tanh_fast(kv.z + qv.z) * wv.z;
                acc += tanh_fast(kv.w + qv.w) * wv.w;
            }
            #pragma unroll
            for (int off = 32; off; off >>= 1) acc += __shfl_down(acc, off);
            if (lane == 0) e = __expf(acc + c0);
        }
        if (lane == 0) esm[r] = e;
    }
    __syncthreads();

    // ---- escore + psum (fixed order, deterministic)
    if (tid < CHK) escore[(size_t)b * TT + t0 + tid] = esm[tid];
    if (tid == 0) {
        float s = 0.0f;
        #pragma unroll
        for (int i = 0; i < CHK; ++i) s += esm[i];
        psum[b * NCH + blockIdx.x] = s;
    }

    // ---- PV: unnormalized partial
    int d4 = tid * 4;
    int tend = min(t0 + CHK, len);
    const float* vbase = value + (size_t)b * TT * DD + d4;
    float4 acc = {0.0f, 0.0f, 0.0f, 0.0f};
    for (int t = t0; t < tend; ++t) {
        float a = esm[t - t0];
        float4 vv = *(const float4*)(vbase + (size_t)t * DD);
        acc.x = fmaf(a, vv.x, acc.x);
        acc.y = fmaf(a, vv.y, acc.y);
        acc.z = fmaf(a, vv.z, acc.z);
        acc.w = fmaf(a, vv.w, acc.w);
    }
    *(float4*)&partial[((size_t)(b * NCH + blockIdx.x)) * DD + d4] = acc;
}

// ---------------------------------------------------------------------------
// blocks 0..127 : ctx[b,d] = (sum live chunks partial)/S
// blocks 128..191: attn[b,t] = (t<len) ? escore/S : 0
__global__ void __launch_bounds__(256) finalize_kernel(
        const float* __restrict__ partial, const float* __restrict__ escore,
        const float* __restrict__ psum, const int* __restrict__ seq_lens,
        float* __restrict__ ctx, float* __restrict__ attn) {
    __shared__ float sinv_sh;
    int bx = blockIdx.x, tid = threadIdx.x;

    if (bx < 128) {
        int b   = bx >> 2;
        int len = seq_lens[b];
        int nch = (len + CHK - 1) / CHK;
        if (tid == 0) {
            float s = 0.0f;
            for (int c = 0; c < nch; ++c) s += psum[b * NCH + c];
            sinv_sh = 1.0f / s;
        }
        __syncthreads();
        float Sinv = sinv_sh;
        int d = (bx & 3) * 256 + tid;
        float acc = 0.0f;
        for (int c = 0; c < nch; ++c)
            acc += partial[((size_t)(b * NCH + c)) * DD + d];
        ctx[(size_t)b * DD + d] = acc * Sinv;
    } else {
        int idx = (bx - 128) * 1024 + tid * 4;    // 64 blocks x 1024 elems
        int b   = idx >> 11;                      // constant within block
        int t   = idx & (TT - 1);
        int len = seq_lens[b];
        int nch = (len + CHK - 1) / CHK;
        if (tid == 0) {
            float s = 0.0f;
            for (int c = 0; c < nch; ++c) s += psum[b * NCH + c];
            sinv_sh = 1.0f / s;
        }
        __syncthreads();
        float Sinv = sinv_sh;
        float4 e = *(const float4*)&escore[(size_t)b * TT + t];
        float4 o;
        o.x = (t + 0 < len) ? e.x * Sinv : 0.0f;
        o.y = (t + 1 < len) ? e.y * Sinv : 0.0f;
        o.z = (t + 2 < len) ? e.z * Sinv : 0.0f;
        o.w = (t + 3 < len) ? e.w * Sinv : 0.0f;
        *(float4*)&attn[(size_t)b * TT + t] = o;
    }
}

// ---------------------------------------------------------------------------
extern "C" void kernel_launch(void* const* d_in, const int* in_sizes, int n_in,
                              void* d_out, int out_size, void* d_ws, size_t ws_size,
                              hipStream_t stream) {
    const float* hidden   = (const float*)d_in[0];
    const float* key      = (const float*)d_in[1];
    const float* value    = (const float*)d_in[2];
    const int*   seq_lens = (const int*)  d_in[3];
    const float* Wq       = (const float*)d_in[4];
    const float* bq       = (const float*)d_in[5];
    const float* W1       = (const float*)d_in[6];
    const float* b1       = (const float*)d_in[7];
    const float* W2       = (const float*)d_in[8];
    const float* b2       = (const float*)d_in[9];

    float* out  = (float*)d_out;
    float* ctx  = out;                 // [32*1024]
    float* attn = out + BB * DD;       // [32*2048]

    float* ws      = (float*)d_ws;
    float* w       = ws;                               // 1024
    float* cb      = ws + 1024;                        // 1 (padded)
    float* query   = ws + 2048;                        // 32768
    float* qpart   = query + BB * DD;                  // 32*32*1024
    float* escore  = qpart + (size_t)QKS * BB * DD;    // 65536
    float* psum    = escore + BB * TT;                 // 32*64 = 2048
    float* partial = psum + BB * NCH;                  // 32*64*1024

    prep_query_kernel<<<dim3(5 + 4 * QKS), dim3(256), 0, stream>>>(
        hidden, Wq, W1, b1, W2, b2, w, cb, qpart);
    qreduce_kernel<<<dim3(BB * DD / 256), dim3(256), 0, stream>>>(qpart, bq, query);
    score_ctx_kernel<<<dim3(NCH, BB), dim3(256), 0, stream>>>(
        key, value, query, w, cb, seq_lens, escore, psum, partial);
    finalize_kernel<<<dim3(192), dim3(256), 0, stream>>>(
        partial, escore, psum, seq_lens, ctx, attn);
}